// Round 1
// baseline (737.123 us; speedup 1.0000x reference)
//
#include <hip/hip_runtime.h>

#define TT 1024
#define CC 128
#define LL 128
#define SS 257      // 2*L+1
#define BLANK 127   // C-1
#define NEG_INF (-1e30f)
#define EPSF 1e-7f

// One block per batch element. 320 threads (5 waves):
//   - thread tid < 257 owns lattice state s = tid
//   - threads 0..127 also load/reduce the y_pred row (one float each)
// Per iteration: exactly one __syncthreads(); all LDS producers write the
// opposite buffer (rowbuf/partial/alpha are double-buffered) from what the
// same iteration reads.
__global__ __launch_bounds__(320) void ctc_kernel(const int* __restrict__ yt,
                                                  const float* __restrict__ yp,
                                                  float* __restrict__ out) {
  const int b = blockIdx.x;
  const int tid = threadIdx.x;

  __shared__ float rowbuf[2][CC];     // (p + eps) for row t, double buffered
  __shared__ float partial[2][2];     // per-wave rowsum partials
  __shared__ float alpha[2][SS + 2];  // +2 front pad: speculated [s-2] is in-bounds
  __shared__ int labels[LL];

  const float* P = yp + (size_t)b * (TT * CC);

  // --- prologue: prefetch rows 0..3 into registers, stage row 0 to LDS ---
  float v[4];
  if (tid < CC) {
#pragma unroll
    for (int j = 0; j < 4; ++j) v[j] = P[j * CC + tid] + EPSF;
    rowbuf[0][tid] = v[0];
    float x = v[0];
#pragma unroll
    for (int off = 32; off > 0; off >>= 1) x += __shfl_down(x, off);
    if ((tid & 63) == 0) partial[0][tid >> 6] = x;
    v[0] = P[4 * CC + tid] + EPSF;  // refill slot 0 with row 4
  }
  if (tid < LL) labels[tid] = yt[b * LL + tid];
  __syncthreads();

  // --- per-thread lattice-state constants ---
  const int s = tid;
  const bool sv = (s < SS);
  int ext = BLANK;  // even states are blank
  int skip = 0;
  if (sv && (s & 1)) {
    const int k = s >> 1;
    ext = labels[k];  // labels are in [0, C-2], never blank
    skip = (k >= 1) && (labels[k] != labels[k - 1]);
  }

  // --- main recursion: iter t computes alpha_t into alpha[t&1] ---
  for (int t0 = 0; t0 < TT; t0 += 4) {
#pragma unroll
    for (int u = 0; u < 4; ++u) {
      const int t = t0 + u;
      const int rb = u & 1;  // == t & 1
      const float rs = 1.0f / (partial[rb][0] + partial[rb][1]);

      if (sv) {
        const float lp = __logf(rowbuf[rb][ext] * rs);
        float a;
        if (t == 0) {
          a = (s < 2) ? lp : NEG_INF;
        } else {
          const float* ap_ = &alpha[rb ^ 1][2];
          const float as = ap_[s];
          const float apv = (s >= 1) ? ap_[s - 1] : NEG_INF;
          const float ak = skip ? ap_[s - 2] : NEG_INF;
          const float m = fmaxf(as, fmaxf(apv, ak));
          const float lse =
              m + __logf(__expf(as - m) + __expf(apv - m) + __expf(ak - m));
          a = lse + lp;
        }
        alpha[rb][2 + s] = a;
      }

      // stage row t+1 (register -> LDS, opposite buffer) + prefetch row t+5
      if (tid < CC && (t + 1 < TT)) {
        const float w = v[(u + 1) & 3];
        rowbuf[rb ^ 1][tid] = w;
        float x = w;
#pragma unroll
        for (int off = 32; off > 0; off >>= 1) x += __shfl_down(x, off);
        if ((tid & 63) == 0) partial[rb ^ 1][tid >> 6] = x;
        if (t + 5 < TT) v[(u + 1) & 3] = P[(size_t)(t + 5) * CC + tid] + EPSF;
      }
      __syncthreads();
    }
  }

  // --- epilogue: loglik = logaddexp(alpha[S-1], alpha[S-2]) ---
  if (tid == 0) {
    const float a1 = alpha[(TT - 1) & 1][2 + SS - 2];
    const float a2 = alpha[(TT - 1) & 1][2 + SS - 1];
    const float m = fmaxf(a1, a2);
    out[b] = -(m + __logf(__expf(a1 - m) + __expf(a2 - m)));
  }
}

extern "C" void kernel_launch(void* const* d_in, const int* in_sizes, int n_in,
                              void* d_out, int out_size, void* d_ws,
                              size_t ws_size, hipStream_t stream) {
  const int* yt = (const int*)d_in[0];
  const float* yp = (const float*)d_in[1];
  float* out = (float*)d_out;
  const int B = in_sizes[0] / LL;  // 128
  hipLaunchKernelGGL(ctc_kernel, dim3(B), dim3(320), 0, stream, yt, yp, out);
}